// Round 12
// baseline (33.652 us; speedup 1.0000x reference)
//
#include <hip/hip_runtime.h>

#define HALF 16
#define IMW  512
#define IMH  512
#define TSZ  32
#define NT   16
#define TPI  256
#define CAP  64

typedef float f32x4 __attribute__((ext_vector_type(4)));

// PROBE DISPATCH: bare streaming-store kernel, fill-like structure.
// 2048 blocks x 256 thr; block b owns a contiguous 32 KB chunk of d_ws;
// each store instruction writes 4 KB contiguous per block. No loads, no
// LDS, no barrier. Measures whether a USER kernel can match
// __amd_rocclr_fillBufferAligned's 6.7 TB/s on this machine.
__global__ __launch_bounds__(256)
void pure_store_kernel(float* __restrict__ dst, int per_block /* f32x4 per block */)
{
    f32x4* base = reinterpret_cast<f32x4*>(dst) + (size_t)blockIdx.x * per_block;
    f32x4 z = {0.0f, 0.0f, 0.0f, 0.0f};
    for (int i = threadIdx.x; i < per_block; i += 256)
        base[i] = z;
}

// Best measured gather (round-4 kernel, byte-identical): one block per 32x32
// tile, LDS landmark list, 4 contiguous px/thread, one f32x4 nt store.
__global__ __launch_bounds__(256)
void lm_gather_kernel(const float* __restrict__ landmarks,  // [B, L, 2]
                      float* __restrict__ out,              // [B, IMH*IMW]
                      int L)
{
    __shared__ float2 slm[CAP];
    __shared__ int sn;

    const int t    = threadIdx.x;
    const int bx   = blockIdx.x;
    const int b    = bx >> 8;            // TPI == 256
    const int tile = bx & (TPI - 1);
    const int tx   = tile & (NT - 1);
    const int ty   = tile >> 4;

    if (t == 0) sn = 0;
    __syncthreads();

    const float2* lmb = reinterpret_cast<const float2*>(landmarks) + (size_t)b * L;
    for (int j = t; j < L; j += 256) {
        float2 lm = lmb[j];
        float x0 = fminf(fmaxf(lm.x, (float)HALF), (float)(IMW - 1 - HALF));
        float x1 = fminf(fmaxf(lm.y, (float)HALF), (float)(IMH - 1 - HALF));
        int i0 = (int)x0;                // coords >= 16 > 0, trunc == floor
        int i1 = (int)x1;
        int tx0 = (i0 - HALF) >> 5;
        int ty0 = (i1 - HALF) >> 5;
        if ((unsigned)(tx - tx0) <= 1u && (unsigned)(ty - ty0) <= 1u) {
            int pos = atomicAdd(&sn, 1);
            if (pos < CAP) slm[pos] = make_float2(x0, x1);
        }
    }
    __syncthreads();
    const int n = min(sn, CAP);

    const int   py  = ty * TSZ + (t >> 3);
    const int   px0 = tx * TSZ + (t & 7) * 4;
    const float fpy = (float)py;

    float acc[4] = {0.0f, 0.0f, 0.0f, 0.0f};
    for (int j = 0; j < n; ++j) {
        float2 e = slm[j];
        int   i0   = (int)e.x;
        int   i1   = (int)e.y;
        float dy   = fpy - e.y;
        float dy2e = dy * dy + 1e-6f;
        bool  in1  = (unsigned)(py - i1 + HALF) <= (unsigned)(2 * HALF);
        #pragma unroll
        for (int c = 0; c < 4; ++c) {
            int   px  = px0 + c;
            float dx  = (float)px - e.x;
            bool  in0 = (unsigned)(px - i0 + HALF) <= (unsigned)(2 * HALF);
            float v = __builtin_amdgcn_rcpf(1.0f + __builtin_amdgcn_sqrtf(dx * dx + dy2e));
            acc[c] += (in0 && in1) ? v : 0.0f;
        }
    }

    float* op = out + (size_t)b * (IMH * IMW) + (size_t)py * IMW + px0;
    f32x4 v4 = { acc[0], acc[1], acc[2], acc[3] };
    __builtin_nontemporal_store(v4, reinterpret_cast<f32x4*>(op));
}

extern "C" void kernel_launch(void* const* d_in, const int* in_sizes, int n_in,
                              void* d_out, int out_size, void* d_ws, size_t ws_size,
                              hipStream_t stream)
{
    // d_in[0] = img (unused by the reference); d_in[1] = landmarks [B, L, 2] f32
    const float* landmarks = (const float*)d_in[1];
    float* out = (float*)d_out;

    const int B = out_size / (IMH * IMW);   // 64
    const int L = in_sizes[1] / (2 * B);    // 106

    // Probe first, from an idle device: 64 MiB of zero-stores into d_ws.
    // grid 2048, per_block = out_size/16/2048 = 8192 f32x4 = 32 KB/block.
    const int nvec4     = out_size / 4;     // 16.78M f32x4 == 64 MiB
    const int per_block = nvec4 / 2048;
    pure_store_kernel<<<2048, 256, 0, stream>>>((float*)d_ws, per_block);

    // Then the unchanged best gather (round 4).
    lm_gather_kernel<<<B * TPI, 256, 0, stream>>>(landmarks, out, L);
}